// Round 1
// baseline (1405.030 us; speedup 1.0000x reference)
//
#include <hip/hip_runtime.h>
#include <hip/hip_bf16.h>
#include <cstdint>

#define NNODES 100000
#define NEDGES 3200000
#define FDIM   512
#define MPAD   100096   // 782 * 128 (pad M so GEMM has no bounds checks)

typedef __bf16 bf16_t;
typedef __bf16 bf16x8 __attribute__((ext_vector_type(8)));
typedef float  f32x4  __attribute__((ext_vector_type(4)));

static __device__ __forceinline__ bf16x8 ld_frag(const ushort* p) {
    return __builtin_bit_cast(bf16x8, *(const uint4*)p);
}

// ---------------- cast / transpose ----------------

// x fp32 [NNODES,512] -> bf16 [MPAD,512], zero-filled pad rows.
__global__ void cast_x_kernel(const float* __restrict__ x, ushort* __restrict__ xb) {
    size_t t = (size_t)blockIdx.x * 256 + threadIdx.x;   // one thread = 4 elems
    size_t base = t * 4;
    int row = (int)(base >> 9);
    ushort4 pk;
    if (row < NNODES) {
        float4 v = *(const float4*)(x + base);
        pk.x = __builtin_bit_cast(ushort, (bf16_t)v.x);
        pk.y = __builtin_bit_cast(ushort, (bf16_t)v.y);
        pk.z = __builtin_bit_cast(ushort, (bf16_t)v.z);
        pk.w = __builtin_bit_cast(ushort, (bf16_t)v.w);
    } else {
        pk.x = pk.y = pk.z = pk.w = 0;
    }
    *(ushort4*)(xb + base) = pk;
}

// weight fp32 [K=512, N=512] -> wt bf16 [N, K] (transposed, row-major)
__global__ void cast_wt_kernel(const float* __restrict__ w, ushort* __restrict__ wt) {
    int t = blockIdx.x * 256 + threadIdx.x;   // 262144 threads
    int n = t >> 9, k = t & 511;
    wt[(size_t)n * 512 + k] = __builtin_bit_cast(ushort, (bf16_t)w[(size_t)k * 512 + n]);
}

// ---------------- GEMM: support = Xbf @ W  (bf16 in, bf16 out, fp32 acc) ----------------
// 128x128 tile / block of 256 threads; 4 waves each own a 64x64 quadrant (4x4 of 16x16).
// LDS layout [quad][row][8] so each fragment is one aligned 16B ds_read (2-way conflicts only).
__global__ __launch_bounds__(256) void gemm_kernel(const ushort* __restrict__ xb,
                                                   const ushort* __restrict__ wt,
                                                   ushort* __restrict__ sup) {
    __shared__ ushort As[4 * 128 * 8];
    __shared__ ushort Bs[4 * 128 * 8];

    const int tid  = threadIdx.x;
    const int m0   = blockIdx.y * 128;
    const int n0   = blockIdx.x * 128;
    const int wave = tid >> 6, lane = tid & 63;
    const int quad = lane >> 4, r16 = lane & 15;
    const int wm = (wave >> 1) * 64, wn = (wave & 1) * 64;

    // staging assignment: transfer L in [0,512): q = L>>7, row = L&127; this thread does L=tid, L=tid+256
    const int qa = tid >> 7, ra = tid & 127;

    f32x4 acc[4][4];
#pragma unroll
    for (int i = 0; i < 4; ++i)
#pragma unroll
        for (int j = 0; j < 4; ++j) acc[i][j] = f32x4{0.f, 0.f, 0.f, 0.f};

    const size_t arow = (size_t)(m0 + ra) * 512;
    const size_t brow = (size_t)(n0 + ra) * 512;

    for (int kc = 0; kc < 16; ++kc) {
        const int k0 = kc * 32;
        __syncthreads();
        *(uint4*)(As + ((qa    ) * 128 + ra) * 8) = *(const uint4*)(xb + arow + k0 + (qa    ) * 8);
        *(uint4*)(As + ((qa + 2) * 128 + ra) * 8) = *(const uint4*)(xb + arow + k0 + (qa + 2) * 8);
        *(uint4*)(Bs + ((qa    ) * 128 + ra) * 8) = *(const uint4*)(wt + brow + k0 + (qa    ) * 8);
        *(uint4*)(Bs + ((qa + 2) * 128 + ra) * 8) = *(const uint4*)(wt + brow + k0 + (qa + 2) * 8);
        __syncthreads();

        bf16x8 af[4], bfr[4];
#pragma unroll
        for (int i = 0; i < 4; ++i) af[i]  = ld_frag(As + (quad * 128 + wm + 16 * i + r16) * 8);
#pragma unroll
        for (int j = 0; j < 4; ++j) bfr[j] = ld_frag(Bs + (quad * 128 + wn + 16 * j + r16) * 8);

#pragma unroll
        for (int i = 0; i < 4; ++i)
#pragma unroll
            for (int j = 0; j < 4; ++j)
                acc[i][j] = __builtin_amdgcn_mfma_f32_16x16x32_bf16(af[i], bfr[j], acc[i][j], 0, 0, 0);
    }

    // epilogue: C/D layout col=lane&15, row=quad*4+reg
#pragma unroll
    for (int i = 0; i < 4; ++i) {
        const int rowb = m0 + wm + 16 * i + quad * 4;
#pragma unroll
        for (int j = 0; j < 4; ++j) {
            const int col = n0 + wn + 16 * j + r16;
            f32x4 v = acc[i][j];
#pragma unroll
            for (int r = 0; r < 4; ++r)
                sup[(size_t)(rowb + r) * 512 + col] = __builtin_bit_cast(ushort, (bf16_t)v[r]);
        }
    }
}

// ---------------- CSR build ----------------

__global__ void zero_cnt_kernel(int* __restrict__ cnt, int* __restrict__ fill) {
    int i = blockIdx.x * 256 + threadIdx.x;
    if (i < NNODES) { cnt[i] = 0; fill[i] = 0; }
}

__global__ void hist_kernel(const int* __restrict__ ei, int* __restrict__ cnt) {
    int e = blockIdx.x * 256 + threadIdx.x;
    if (e < NEDGES) atomicAdd(&cnt[ei[e]], 1);
}

// single-block exclusive scan over NNODES counts -> row_ptr
__global__ __launch_bounds__(1024) void scan_kernel(const int* __restrict__ cnt, int* __restrict__ ptr) {
    __shared__ int sums[1024];
    const int t = threadIdx.x;
    const int CH = (NNODES + 1023) / 1024;   // 98
    const int b = t * CH;
    const int e = min(b + CH, NNODES);
    int s = 0;
    for (int i = b; i < e; ++i) s += cnt[i];
    sums[t] = s;
    __syncthreads();
    for (int off = 1; off < 1024; off <<= 1) {
        int v = (t >= off) ? sums[t - off] : 0;
        __syncthreads();
        sums[t] += v;
        __syncthreads();
    }
    int run = sums[t] - s;   // exclusive prefix of this chunk
    for (int i = b; i < e; ++i) { ptr[i] = run; run += cnt[i]; }
    if (t == 0) ptr[NNODES] = NEDGES;
}

__global__ void scatter_kernel(const int* __restrict__ ei, const float* __restrict__ ew,
                               const int* __restrict__ ptr, int* __restrict__ fill,
                               int* __restrict__ cols, float* __restrict__ wsrt) {
    int e = blockIdx.x * 256 + threadIdx.x;
    if (e < NEDGES) {
        int r = ei[e];
        int pos = ptr[r] + atomicAdd(&fill[r], 1);
        cols[pos] = ei[NEDGES + e];
        wsrt[pos] = ew[e];
    }
}

// ---------------- SpMM: out[r] = sum_e w_e * sup[col_e] + bias ----------------
// one wave per row; lane covers 8 features (16B bf16 gather, coalesced 1KB/wave/edge).
// Edge loop unrolled x4 with all 4 gathers issued before any use -> 4x memory-level
// parallelism (was latency-bound: 1 dependent gather in flight, VALUBusy 23%).
__global__ __launch_bounds__(256) void spmm_kernel(const ushort* __restrict__ sup,
                                                   const int* __restrict__ ptr,
                                                   const int* __restrict__ cols,
                                                   const float* __restrict__ wsrt,
                                                   const float* __restrict__ bias,
                                                   float* __restrict__ out) {
    const int row  = blockIdx.x * 4 + (threadIdx.x >> 6);
    const int lane = threadIdx.x & 63;
    const int fo   = lane * 8;
    const int start = ptr[row], end = ptr[row + 1];

    float acc[8];
#pragma unroll
    for (int j = 0; j < 8; ++j) acc[j] = 0.f;

    int i = start;
    for (; i + 4 <= end; i += 4) {
        // issue all scalar loads, then all 4 independent gathers, before any FMA
        const int   c0 = cols[i],     c1 = cols[i + 1], c2 = cols[i + 2], c3 = cols[i + 3];
        const float w0 = wsrt[i],     w1 = wsrt[i + 1], w2 = wsrt[i + 2], w3 = wsrt[i + 3];
        const bf16x8 s0 = __builtin_bit_cast(bf16x8, *(const uint4*)(sup + (size_t)c0 * 512 + fo));
        const bf16x8 s1 = __builtin_bit_cast(bf16x8, *(const uint4*)(sup + (size_t)c1 * 512 + fo));
        const bf16x8 s2 = __builtin_bit_cast(bf16x8, *(const uint4*)(sup + (size_t)c2 * 512 + fo));
        const bf16x8 s3 = __builtin_bit_cast(bf16x8, *(const uint4*)(sup + (size_t)c3 * 512 + fo));
#pragma unroll
        for (int j = 0; j < 8; ++j) {
            acc[j] += w0 * (float)s0[j];
            acc[j] += w1 * (float)s1[j];
            acc[j] += w2 * (float)s2[j];
            acc[j] += w3 * (float)s3[j];
        }
    }
    for (; i < end; ++i) {
        const int c = cols[i];
        const float w = wsrt[i];
        bf16x8 sv = __builtin_bit_cast(bf16x8, *(const uint4*)(sup + (size_t)c * 512 + fo));
#pragma unroll
        for (int j = 0; j < 8; ++j) acc[j] += w * (float)sv[j];
    }

    const float4 b0 = *(const float4*)(bias + fo);
    const float4 b1 = *(const float4*)(bias + fo + 4);
    float* op = out + (size_t)row * 512 + fo;
    *(float4*)(op)     = make_float4(acc[0] + b0.x, acc[1] + b0.y, acc[2] + b0.z, acc[3] + b0.w);
    *(float4*)(op + 4) = make_float4(acc[4] + b1.x, acc[5] + b1.y, acc[6] + b1.z, acc[7] + b1.w);
}

// ---------------- launch ----------------

extern "C" void kernel_launch(void* const* d_in, const int* in_sizes, int n_in,
                              void* d_out, int out_size, void* d_ws, size_t ws_size,
                              hipStream_t stream) {
    const float* x    = (const float*)d_in[0];
    const int*   ei   = (const int*)d_in[1];     // [2, E]
    const float* ew   = (const float*)d_in[2];
    const float* w    = (const float*)d_in[3];
    const float* bias = (const float*)d_in[4];
    float* out = (float*)d_out;

    char* ws = (char*)d_ws;
    size_t off = 0;
    auto take = [&](size_t bytes) { char* p = ws + off; off = (off + bytes + 255) & ~(size_t)255; return p; };

    ushort* xb   = (ushort*)take((size_t)MPAD * FDIM * 2);   // 102.5 MB
    ushort* sup  = (ushort*)take((size_t)MPAD * FDIM * 2);   // 102.5 MB
    ushort* wt   = (ushort*)take((size_t)FDIM * FDIM * 2);   // 0.5 MB
    int*   cnt   = (int*)take((size_t)NNODES * 4);
    int*   ptr   = (int*)take((size_t)(NNODES + 1) * 4);
    int*   fill  = (int*)take((size_t)NNODES * 4);
    int*   cols  = (int*)take((size_t)NEDGES * 4);           // 12.8 MB
    float* wsrt  = (float*)take((size_t)NEDGES * 4);         // 12.8 MB

    hipLaunchKernelGGL(cast_x_kernel, dim3((MPAD * FDIM / 4) / 256), dim3(256), 0, stream, x, xb);
    hipLaunchKernelGGL(cast_wt_kernel, dim3(1024), dim3(256), 0, stream, w, wt);
    hipLaunchKernelGGL(gemm_kernel, dim3(FDIM / 128, MPAD / 128), dim3(256), 0, stream, xb, wt, sup);
    hipLaunchKernelGGL(zero_cnt_kernel, dim3((NNODES + 255) / 256), dim3(256), 0, stream, cnt, fill);
    hipLaunchKernelGGL(hist_kernel, dim3(NEDGES / 256), dim3(256), 0, stream, ei, cnt);
    hipLaunchKernelGGL(scan_kernel, dim3(1), dim3(1024), 0, stream, cnt, ptr);
    hipLaunchKernelGGL(scatter_kernel, dim3(NEDGES / 256), dim3(256), 0, stream, ei, ew, ptr, fill, cols, wsrt);
    hipLaunchKernelGGL(spmm_kernel, dim3(NNODES / 4), dim3(256), 0, stream, sup, ptr, cols, wsrt, bias, out);
}

// Round 3
// 1377.186 us; speedup vs baseline: 1.0202x; 1.0202x over previous
//
#include <hip/hip_runtime.h>
#include <hip/hip_bf16.h>
#include <cstdint>

#define NNODES 100000
#define NEDGES 3200000
#define FDIM   512
#define FHALF  256
#define MPAD   100096   // 782 * 128 (pad M so GEMM has no bounds checks)

typedef __bf16 bf16_t;
typedef __bf16 bf16x8 __attribute__((ext_vector_type(8)));
typedef __bf16 bf16x4 __attribute__((ext_vector_type(4)));
typedef float  f32x4  __attribute__((ext_vector_type(4)));

static __device__ __forceinline__ bf16x8 ld_frag(const ushort* p) {
    return __builtin_bit_cast(bf16x8, *(const uint4*)p);
}

// global->LDS direct (async DMA), 16B per lane. LDS dest must be
// wave-uniform base + lane*16 — our staging layout is linear in tid so this holds.
typedef __attribute__((address_space(3))) ushort as3_ushort;
typedef __attribute__((address_space(1))) const ushort as1_ushort;
static __device__ __forceinline__ void gl_lds16(const ushort* g, ushort* l) {
    __builtin_amdgcn_global_load_lds((as1_ushort*)(uintptr_t)g,
                                     (as3_ushort*)(uintptr_t)l, 16, 0, 0);
}

// ---------------- cast / transpose ----------------

// x fp32 [NNODES,512] -> bf16 [MPAD,512], zero-filled pad rows.
__global__ void cast_x_kernel(const float* __restrict__ x, ushort* __restrict__ xb) {
    size_t t = (size_t)blockIdx.x * 256 + threadIdx.x;   // one thread = 4 elems
    size_t base = t * 4;
    int row = (int)(base >> 9);
    ushort4 pk;
    if (row < NNODES) {
        float4 v = *(const float4*)(x + base);
        pk.x = __builtin_bit_cast(ushort, (bf16_t)v.x);
        pk.y = __builtin_bit_cast(ushort, (bf16_t)v.y);
        pk.z = __builtin_bit_cast(ushort, (bf16_t)v.z);
        pk.w = __builtin_bit_cast(ushort, (bf16_t)v.w);
    } else {
        pk.x = pk.y = pk.z = pk.w = 0;
    }
    *(ushort4*)(xb + base) = pk;
}

// weight fp32 [K=512, N=512] -> wt bf16 [N, K] (transposed, row-major)
__global__ void cast_wt_kernel(const float* __restrict__ w, ushort* __restrict__ wt) {
    int t = blockIdx.x * 256 + threadIdx.x;   // 262144 threads
    int n = t >> 9, k = t & 511;
    wt[(size_t)n * 512 + k] = __builtin_bit_cast(ushort, (bf16_t)w[(size_t)k * 512 + n]);
}

// ---------------- GEMM: support = Xbf @ W  (bf16 in, bf16 out, fp32 acc) ----------------
// 128x128 tile / block of 256 threads; 4 waves each own a 64x64 quadrant (4x4 of 16x16).
// LDS layout [quad][row][8]: fragment = one aligned 16B ds_read; staging byte offset
// is tid*16 (linear), so global_load_lds width-16 applies directly (m97 pattern).
// Output written feature-split: sup[h][row][256], h = col>>8 (for spmm locality).
__global__ __launch_bounds__(256) void gemm_kernel(const ushort* __restrict__ xb,
                                                   const ushort* __restrict__ wt,
                                                   ushort* __restrict__ sup) {
    __shared__ ushort As[4 * 128 * 8];
    __shared__ ushort Bs[4 * 128 * 8];

    const int tid  = threadIdx.x;
    const int m0   = blockIdx.y * 128;
    const int n0   = blockIdx.x * 128;
    const int wave = tid >> 6, lane = tid & 63;
    const int quad = lane >> 4, r16 = lane & 15;
    const int wm = (wave >> 1) * 64, wn = (wave & 1) * 64;

    // staging: transfer L in [0,512): this thread does L=tid and L=tid+256
    const int qa = tid >> 7, ra = tid & 127;

    f32x4 acc[4][4];
#pragma unroll
    for (int i = 0; i < 4; ++i)
#pragma unroll
        for (int j = 0; j < 4; ++j) acc[i][j] = f32x4{0.f, 0.f, 0.f, 0.f};

    const size_t arow = (size_t)(m0 + ra) * 512;
    const size_t brow = (size_t)(n0 + ra) * 512;

    for (int kc = 0; kc < 16; ++kc) {
        const int k0 = kc * 32;
        __syncthreads();
        // As/Bs byte offset tid*16 and (tid+256)*16 == wave-uniform + lane*16
        gl_lds16(xb + arow + k0 + (qa    ) * 8, As + (size_t)tid * 8);
        gl_lds16(xb + arow + k0 + (qa + 2) * 8, As + (size_t)(tid + 256) * 8);
        gl_lds16(wt + brow + k0 + (qa    ) * 8, Bs + (size_t)tid * 8);
        gl_lds16(wt + brow + k0 + (qa + 2) * 8, Bs + (size_t)(tid + 256) * 8);
        __syncthreads();   // compiler drains vmcnt before s_barrier

        bf16x8 af[4], bfr[4];
#pragma unroll
        for (int i = 0; i < 4; ++i) af[i]  = ld_frag(As + (quad * 128 + wm + 16 * i + r16) * 8);
#pragma unroll
        for (int j = 0; j < 4; ++j) bfr[j] = ld_frag(Bs + (quad * 128 + wn + 16 * j + r16) * 8);

#pragma unroll
        for (int i = 0; i < 4; ++i)
#pragma unroll
            for (int j = 0; j < 4; ++j)
                acc[i][j] = __builtin_amdgcn_mfma_f32_16x16x32_bf16(af[i], bfr[j], acc[i][j], 0, 0, 0);
    }

    // epilogue: C/D layout col=lane&15, row=quad*4+reg; write to split layout
#pragma unroll
    for (int i = 0; i < 4; ++i) {
        const int rowb = m0 + wm + 16 * i + quad * 4;
#pragma unroll
        for (int j = 0; j < 4; ++j) {
            const int col = n0 + wn + 16 * j + r16;
            const size_t base = (size_t)(col >> 8) * MPAD * FHALF + (col & 255);
            f32x4 v = acc[i][j];
#pragma unroll
            for (int r = 0; r < 4; ++r)
                sup[base + (size_t)(rowb + r) * FHALF] = __builtin_bit_cast(ushort, (bf16_t)v[r]);
        }
    }
}

// ---------------- CSR build ----------------

__global__ void zero_cnt_kernel(int* __restrict__ cnt, int* __restrict__ fill) {
    int i = blockIdx.x * 256 + threadIdx.x;
    if (i < NNODES) { cnt[i] = 0; fill[i] = 0; }
}

__global__ void hist_kernel(const int* __restrict__ ei, int* __restrict__ cnt) {
    int e = blockIdx.x * 256 + threadIdx.x;
    if (e < NEDGES) atomicAdd(&cnt[ei[e]], 1);
}

// single-block exclusive scan over NNODES counts -> row_ptr
__global__ __launch_bounds__(1024) void scan_kernel(const int* __restrict__ cnt, int* __restrict__ ptr) {
    __shared__ int sums[1024];
    const int t = threadIdx.x;
    const int CH = (NNODES + 1023) / 1024;   // 98
    const int b = t * CH;
    const int e = min(b + CH, NNODES);
    int s = 0;
    for (int i = b; i < e; ++i) s += cnt[i];
    sums[t] = s;
    __syncthreads();
    for (int off = 1; off < 1024; off <<= 1) {
        int v = (t >= off) ? sums[t - off] : 0;
        __syncthreads();
        sums[t] += v;
        __syncthreads();
    }
    int run = sums[t] - s;   // exclusive prefix of this chunk
    for (int i = b; i < e; ++i) { ptr[i] = run; run += cnt[i]; }
    if (t == 0) ptr[NNODES] = NEDGES;
}

__global__ void scatter_kernel(const int* __restrict__ ei, const float* __restrict__ ew,
                               const int* __restrict__ ptr, int* __restrict__ fill,
                               int* __restrict__ cols, float* __restrict__ wsrt) {
    int e = blockIdx.x * 256 + threadIdx.x;
    if (e < NEDGES) {
        int r = ei[e];
        int pos = ptr[r] + atomicAdd(&fill[r], 1);
        cols[pos] = ei[NEDGES + e];
        wsrt[pos] = ew[e];
    }
}

// ---------------- SpMM: out[r] = sum_e w_e * sup[col_e] + bias ----------------
// Feature-split: sup is [2][MPAD][256] bf16; blockIdx.y = half (slow dispatch axis,
// so the two 51 MB gather footprints are processed ~sequentially -> higher L2/LLC
// hit rate than one 102 MB footprint). One wave per row; lane covers 4 features (8B).
// out written nontemporal so the 200 MB stream doesn't evict sup from LLC.
__global__ __launch_bounds__(256) void spmm_kernel(const ushort* __restrict__ sup,
                                                   const int* __restrict__ ptr,
                                                   const int* __restrict__ cols,
                                                   const float* __restrict__ wsrt,
                                                   const float* __restrict__ bias,
                                                   float* __restrict__ out) {
    const int row  = blockIdx.x * 4 + (threadIdx.x >> 6);
    const int half = blockIdx.y;
    const ushort* suph = sup + (size_t)half * MPAD * FHALF;
    const int lane = threadIdx.x & 63;
    const int fo   = lane * 4;               // feature offset within half
    const int start = ptr[row], end = ptr[row + 1];

    float acc[4];
#pragma unroll
    for (int j = 0; j < 4; ++j) acc[j] = 0.f;

    int i = start;
    for (; i + 4 <= end; i += 4) {
        const int   c0 = cols[i],     c1 = cols[i + 1], c2 = cols[i + 2], c3 = cols[i + 3];
        const float w0 = wsrt[i],     w1 = wsrt[i + 1], w2 = wsrt[i + 2], w3 = wsrt[i + 3];
        const bf16x4 s0 = __builtin_bit_cast(bf16x4, *(const uint2*)(suph + (size_t)c0 * FHALF + fo));
        const bf16x4 s1 = __builtin_bit_cast(bf16x4, *(const uint2*)(suph + (size_t)c1 * FHALF + fo));
        const bf16x4 s2 = __builtin_bit_cast(bf16x4, *(const uint2*)(suph + (size_t)c2 * FHALF + fo));
        const bf16x4 s3 = __builtin_bit_cast(bf16x4, *(const uint2*)(suph + (size_t)c3 * FHALF + fo));
#pragma unroll
        for (int j = 0; j < 4; ++j) {
            acc[j] += w0 * (float)s0[j];
            acc[j] += w1 * (float)s1[j];
            acc[j] += w2 * (float)s2[j];
            acc[j] += w3 * (float)s3[j];
        }
    }
    for (; i < end; ++i) {
        const int c = cols[i];
        const float w = wsrt[i];
        const bf16x4 sv = __builtin_bit_cast(bf16x4, *(const uint2*)(suph + (size_t)c * FHALF + fo));
#pragma unroll
        for (int j = 0; j < 4; ++j) acc[j] += w * (float)sv[j];
    }

    const int fglob = half * FHALF + fo;
    const float4 b0 = *(const float4*)(bias + fglob);
    f32x4 o;
    o[0] = acc[0] + b0.x; o[1] = acc[1] + b0.y; o[2] = acc[2] + b0.z; o[3] = acc[3] + b0.w;
    __builtin_nontemporal_store(o, (f32x4*)(out + (size_t)row * 512 + fglob));
}

// ---------------- launch ----------------

extern "C" void kernel_launch(void* const* d_in, const int* in_sizes, int n_in,
                              void* d_out, int out_size, void* d_ws, size_t ws_size,
                              hipStream_t stream) {
    const float* x    = (const float*)d_in[0];
    const int*   ei   = (const int*)d_in[1];     // [2, E]
    const float* ew   = (const float*)d_in[2];
    const float* w    = (const float*)d_in[3];
    const float* bias = (const float*)d_in[4];
    float* out = (float*)d_out;

    char* ws = (char*)d_ws;
    size_t off = 0;
    auto take = [&](size_t bytes) { char* p = ws + off; off = (off + bytes + 255) & ~(size_t)255; return p; };

    ushort* xb   = (ushort*)take((size_t)MPAD * FDIM * 2);   // 102.5 MB
    ushort* sup  = (ushort*)take((size_t)MPAD * FDIM * 2);   // 102.5 MB (2 x [MPAD][256])
    ushort* wt   = (ushort*)take((size_t)FDIM * FDIM * 2);   // 0.5 MB
    int*   cnt   = (int*)take((size_t)NNODES * 4);
    int*   ptr   = (int*)take((size_t)(NNODES + 1) * 4);
    int*   fill  = (int*)take((size_t)NNODES * 4);
    int*   cols  = (int*)take((size_t)NEDGES * 4);           // 12.8 MB
    float* wsrt  = (float*)take((size_t)NEDGES * 4);         // 12.8 MB

    hipLaunchKernelGGL(cast_x_kernel, dim3((MPAD * FDIM / 4) / 256), dim3(256), 0, stream, x, xb);
    hipLaunchKernelGGL(cast_wt_kernel, dim3(1024), dim3(256), 0, stream, w, wt);
    hipLaunchKernelGGL(gemm_kernel, dim3(FDIM / 128, MPAD / 128), dim3(256), 0, stream, xb, wt, sup);
    hipLaunchKernelGGL(zero_cnt_kernel, dim3((NNODES + 255) / 256), dim3(256), 0, stream, cnt, fill);
    hipLaunchKernelGGL(hist_kernel, dim3(NEDGES / 256), dim3(256), 0, stream, ei, cnt);
    hipLaunchKernelGGL(scan_kernel, dim3(1), dim3(1024), 0, stream, cnt, ptr);
    hipLaunchKernelGGL(scatter_kernel, dim3(NEDGES / 256), dim3(256), 0, stream, ei, ew, ptr, fill, cols, wsrt);
    hipLaunchKernelGGL(spmm_kernel, dim3(NNODES / 4, 2), dim3(256), 0, stream, sup, ptr, cols, wsrt, bias, out);
}

// Round 4
// 1263.872 us; speedup vs baseline: 1.1117x; 1.0897x over previous
//
#include <hip/hip_runtime.h>
#include <hip/hip_bf16.h>
#include <cstdint>

#define NNODES 100000
#define NEDGES 3200000
#define FDIM   512
#define FHALF  256
#define MPAD   100096   // 782 * 128 (pad M so GEMM has no bounds checks)

typedef __bf16 bf16_t;
typedef __bf16 bf16x8 __attribute__((ext_vector_type(8)));
typedef __bf16 bf16x4 __attribute__((ext_vector_type(4)));
typedef float  f32x4  __attribute__((ext_vector_type(4)));

static __device__ __forceinline__ bf16x8 ld_frag(const ushort* p) {
    return __builtin_bit_cast(bf16x8, *(const uint4*)p);
}

// global->LDS direct (async DMA), 16B per lane. LDS dest must be
// wave-uniform base + lane*16 — our staging layout is linear in tid so this holds.
typedef __attribute__((address_space(3))) ushort as3_ushort;
typedef __attribute__((address_space(1))) const ushort as1_ushort;
static __device__ __forceinline__ void gl_lds16(const ushort* g, ushort* l) {
    __builtin_amdgcn_global_load_lds((as1_ushort*)(uintptr_t)g,
                                     (as3_ushort*)(uintptr_t)l, 16, 0, 0);
}

// ---------------- cast / transpose ----------------

// x fp32 [NNODES,512] -> bf16 [MPAD,512], zero-filled pad rows.
__global__ void cast_x_kernel(const float* __restrict__ x, ushort* __restrict__ xb) {
    size_t t = (size_t)blockIdx.x * 256 + threadIdx.x;   // one thread = 4 elems
    size_t base = t * 4;
    int row = (int)(base >> 9);
    ushort4 pk;
    if (row < NNODES) {
        float4 v = *(const float4*)(x + base);
        pk.x = __builtin_bit_cast(ushort, (bf16_t)v.x);
        pk.y = __builtin_bit_cast(ushort, (bf16_t)v.y);
        pk.z = __builtin_bit_cast(ushort, (bf16_t)v.z);
        pk.w = __builtin_bit_cast(ushort, (bf16_t)v.w);
    } else {
        pk.x = pk.y = pk.z = pk.w = 0;
    }
    *(ushort4*)(xb + base) = pk;
}

// weight fp32 [K=512, N=512] -> wt bf16 [N, K] (transposed, row-major)
__global__ void cast_wt_kernel(const float* __restrict__ w, ushort* __restrict__ wt) {
    int t = blockIdx.x * 256 + threadIdx.x;   // 262144 threads
    int n = t >> 9, k = t & 511;
    wt[(size_t)n * 512 + k] = __builtin_bit_cast(ushort, (bf16_t)w[(size_t)k * 512 + n]);
}

// ---------------- GEMM: support = Xbf @ W  (bf16 in, bf16 out, fp32 acc) ----------------
// 128x128 tile / block of 256 threads; 4 waves each own a 64x64 quadrant (4x4 of 16x16).
// LDS layout [quad][row][8]: fragment = one aligned 16B ds_read; staging byte offset
// is tid*16 (linear), so global_load_lds width-16 applies directly (m97 pattern).
// Output written feature-split: sup[h][row][256], h = col>>8 (for spmm locality).
__global__ __launch_bounds__(256) void gemm_kernel(const ushort* __restrict__ xb,
                                                   const ushort* __restrict__ wt,
                                                   ushort* __restrict__ sup) {
    __shared__ ushort As[4 * 128 * 8];
    __shared__ ushort Bs[4 * 128 * 8];

    const int tid  = threadIdx.x;
    const int m0   = blockIdx.y * 128;
    const int n0   = blockIdx.x * 128;
    const int wave = tid >> 6, lane = tid & 63;
    const int quad = lane >> 4, r16 = lane & 15;
    const int wm = (wave >> 1) * 64, wn = (wave & 1) * 64;

    // staging: transfer L in [0,512): this thread does L=tid and L=tid+256
    const int qa = tid >> 7, ra = tid & 127;

    f32x4 acc[4][4];
#pragma unroll
    for (int i = 0; i < 4; ++i)
#pragma unroll
        for (int j = 0; j < 4; ++j) acc[i][j] = f32x4{0.f, 0.f, 0.f, 0.f};

    const size_t arow = (size_t)(m0 + ra) * 512;
    const size_t brow = (size_t)(n0 + ra) * 512;

    for (int kc = 0; kc < 16; ++kc) {
        const int k0 = kc * 32;
        __syncthreads();
        // As/Bs byte offset tid*16 and (tid+256)*16 == wave-uniform + lane*16
        gl_lds16(xb + arow + k0 + (qa    ) * 8, As + (size_t)tid * 8);
        gl_lds16(xb + arow + k0 + (qa + 2) * 8, As + (size_t)(tid + 256) * 8);
        gl_lds16(wt + brow + k0 + (qa    ) * 8, Bs + (size_t)tid * 8);
        gl_lds16(wt + brow + k0 + (qa + 2) * 8, Bs + (size_t)(tid + 256) * 8);
        __syncthreads();   // compiler drains vmcnt before s_barrier

        bf16x8 af[4], bfr[4];
#pragma unroll
        for (int i = 0; i < 4; ++i) af[i]  = ld_frag(As + (quad * 128 + wm + 16 * i + r16) * 8);
#pragma unroll
        for (int j = 0; j < 4; ++j) bfr[j] = ld_frag(Bs + (quad * 128 + wn + 16 * j + r16) * 8);

#pragma unroll
        for (int i = 0; i < 4; ++i)
#pragma unroll
            for (int j = 0; j < 4; ++j)
                acc[i][j] = __builtin_amdgcn_mfma_f32_16x16x32_bf16(af[i], bfr[j], acc[i][j], 0, 0, 0);
    }

    // epilogue: C/D layout col=lane&15, row=quad*4+reg; write to split layout
#pragma unroll
    for (int i = 0; i < 4; ++i) {
        const int rowb = m0 + wm + 16 * i + quad * 4;
#pragma unroll
        for (int j = 0; j < 4; ++j) {
            const int col = n0 + wn + 16 * j + r16;
            const size_t base = (size_t)(col >> 8) * MPAD * FHALF + (col & 255);
            f32x4 v = acc[i][j];
#pragma unroll
            for (int r = 0; r < 4; ++r)
                sup[base + (size_t)(rowb + r) * FHALF] = __builtin_bit_cast(ushort, (bf16_t)v[r]);
        }
    }
}

// ---------------- CSR build ----------------

__global__ void hist_kernel(const int* __restrict__ ei, int* __restrict__ cnt) {
    int e = blockIdx.x * 256 + threadIdx.x;
    if (e < NEDGES) atomicAdd(&cnt[ei[e]], 1);
}

// single-block exclusive scan over NNODES counts -> row_ptr.
// int4 vectorized: 25 16B loads per thread (was 98 scalar dependent loads).
__global__ __launch_bounds__(1024) void scan_kernel(const int* __restrict__ cnt, int* __restrict__ ptr) {
    __shared__ int sums[1024];
    const int t = threadIdx.x;
    const int CH = 100;                 // 1000 threads x 100 = 100000 exactly
    const int b = t * CH;
    int s = 0;
    if (t < 1000) {
        const int4* p = (const int4*)(cnt + b);
#pragma unroll
        for (int i = 0; i < 25; ++i) { int4 v = p[i]; s += v.x + v.y + v.z + v.w; }
    }
    sums[t] = s;
    __syncthreads();
    for (int off = 1; off < 1024; off <<= 1) {
        int v = (t >= off) ? sums[t - off] : 0;
        __syncthreads();
        sums[t] += v;
        __syncthreads();
    }
    if (t < 1000) {
        int run = sums[t] - s;          // exclusive prefix of this chunk
        const int4* p = (const int4*)(cnt + b);
        int4* q = (int4*)(ptr + b);
#pragma unroll
        for (int i = 0; i < 25; ++i) {
            int4 c = p[i];
            int4 r;
            r.x = run; r.y = run + c.x; r.z = r.y + c.y; r.w = r.z + c.z;
            q[i] = r;
            run = r.w + c.w;
        }
    }
    if (t == 0) ptr[NNODES] = NEDGES;
}

__global__ void scatter_kernel(const int* __restrict__ ei, const float* __restrict__ ew,
                               const int* __restrict__ ptr, int* __restrict__ fill,
                               int* __restrict__ cols, float* __restrict__ wsrt) {
    int e = blockIdx.x * 256 + threadIdx.x;
    if (e < NEDGES) {
        int r = ei[e];
        int pos = ptr[r] + atomicAdd(&fill[r], 1);
        cols[pos] = ei[NEDGES + e];
        wsrt[pos] = ew[e];
    }
}

// ---------------- SpMM: out[r] = sum_e w_e * sup[col_e] + bias ----------------
// Feature-split: sup is [2][MPAD][256] bf16; launched once per half (two dispatches:
// strict sequencing of the two 51 MB gather passes + per-dispatch profiling visibility).
// One wave per row; lane covers 4 features (8B gathers). out written nontemporal.
__global__ __launch_bounds__(256) void spmm_kernel(const ushort* __restrict__ sup,
                                                   const int* __restrict__ ptr,
                                                   const int* __restrict__ cols,
                                                   const float* __restrict__ wsrt,
                                                   const float* __restrict__ bias,
                                                   float* __restrict__ out,
                                                   int half) {
    const int row  = blockIdx.x * 4 + (threadIdx.x >> 6);
    const ushort* suph = sup + (size_t)half * MPAD * FHALF;
    const int lane = threadIdx.x & 63;
    const int fo   = lane * 4;               // feature offset within half
    const int start = ptr[row], end = ptr[row + 1];

    float acc[4];
#pragma unroll
    for (int j = 0; j < 4; ++j) acc[j] = 0.f;

    int i = start;
    for (; i + 4 <= end; i += 4) {
        const int   c0 = cols[i],     c1 = cols[i + 1], c2 = cols[i + 2], c3 = cols[i + 3];
        const float w0 = wsrt[i],     w1 = wsrt[i + 1], w2 = wsrt[i + 2], w3 = wsrt[i + 3];
        const bf16x4 s0 = __builtin_bit_cast(bf16x4, *(const uint2*)(suph + (size_t)c0 * FHALF + fo));
        const bf16x4 s1 = __builtin_bit_cast(bf16x4, *(const uint2*)(suph + (size_t)c1 * FHALF + fo));
        const bf16x4 s2 = __builtin_bit_cast(bf16x4, *(const uint2*)(suph + (size_t)c2 * FHALF + fo));
        const bf16x4 s3 = __builtin_bit_cast(bf16x4, *(const uint2*)(suph + (size_t)c3 * FHALF + fo));
#pragma unroll
        for (int j = 0; j < 4; ++j) {
            acc[j] += w0 * (float)s0[j];
            acc[j] += w1 * (float)s1[j];
            acc[j] += w2 * (float)s2[j];
            acc[j] += w3 * (float)s3[j];
        }
    }
    for (; i < end; ++i) {
        const int c = cols[i];
        const float w = wsrt[i];
        const bf16x4 sv = __builtin_bit_cast(bf16x4, *(const uint2*)(suph + (size_t)c * FHALF + fo));
#pragma unroll
        for (int j = 0; j < 4; ++j) acc[j] += w * (float)sv[j];
    }

    const int fglob = half * FHALF + fo;
    const float4 b0 = *(const float4*)(bias + fglob);
    f32x4 o;
    o[0] = acc[0] + b0.x; o[1] = acc[1] + b0.y; o[2] = acc[2] + b0.z; o[3] = acc[3] + b0.w;
    __builtin_nontemporal_store(o, (f32x4*)(out + (size_t)row * 512 + fglob));
}

// ---------------- launch ----------------

extern "C" void kernel_launch(void* const* d_in, const int* in_sizes, int n_in,
                              void* d_out, int out_size, void* d_ws, size_t ws_size,
                              hipStream_t stream) {
    const float* x    = (const float*)d_in[0];
    const int*   ei   = (const int*)d_in[1];     // [2, E]
    const float* ew   = (const float*)d_in[2];
    const float* w    = (const float*)d_in[3];
    const float* bias = (const float*)d_in[4];
    float* out = (float*)d_out;

    char* ws = (char*)d_ws;
    size_t off = 0;
    auto take = [&](size_t bytes) { char* p = ws + off; off = (off + bytes + 255) & ~(size_t)255; return p; };

    ushort* xb   = (ushort*)take((size_t)MPAD * FDIM * 2);   // 102.5 MB
    ushort* sup  = (ushort*)take((size_t)MPAD * FDIM * 2);   // 102.5 MB (2 x [MPAD][256])
    ushort* wt   = (ushort*)take((size_t)FDIM * FDIM * 2);   // 0.5 MB
    int*   cnt   = (int*)take((size_t)NNODES * 4);           // cnt+fill adjacent -> one memset
    int*   fill  = (int*)take((size_t)NNODES * 4);
    int*   ptr   = (int*)take((size_t)(NNODES + 1) * 4);
    int*   cols  = (int*)take((size_t)NEDGES * 4);           // 12.8 MB
    float* wsrt  = (float*)take((size_t)NEDGES * 4);         // 12.8 MB

    // zero cnt..fill in one memset (span includes the 128B alignment pad between them)
    hipMemsetAsync(cnt, 0, (size_t)((char*)fill - (char*)cnt) + (size_t)NNODES * 4, stream);

    hipLaunchKernelGGL(cast_x_kernel, dim3((MPAD * FDIM / 4) / 256), dim3(256), 0, stream, x, xb);
    hipLaunchKernelGGL(cast_wt_kernel, dim3(1024), dim3(256), 0, stream, w, wt);
    hipLaunchKernelGGL(gemm_kernel, dim3(FDIM / 128, MPAD / 128), dim3(256), 0, stream, xb, wt, sup);
    hipLaunchKernelGGL(hist_kernel, dim3(NEDGES / 256), dim3(256), 0, stream, ei, cnt);
    hipLaunchKernelGGL(scan_kernel, dim3(1), dim3(1024), 0, stream, cnt, ptr);
    hipLaunchKernelGGL(scatter_kernel, dim3(NEDGES / 256), dim3(256), 0, stream, ei, ew, ptr, fill, cols, wsrt);
    hipLaunchKernelGGL(spmm_kernel, dim3(NNODES / 4), dim3(256), 0, stream, sup, ptr, cols, wsrt, bias, out, 0);
    hipLaunchKernelGGL(spmm_kernel, dim3(NNODES / 4), dim3(256), 0, stream, sup, ptr, cols, wsrt, bias, out, 1);
}

// Round 6
// 1223.101 us; speedup vs baseline: 1.1487x; 1.0333x over previous
//
#include <hip/hip_runtime.h>
#include <hip/hip_bf16.h>
#include <cstdint>

#define NNODES 100000
#define NEDGES 3200000
#define FDIM   512
#define FHALF  256
#define MPAD   100096   // 782 * 128 (pad M so GEMM has no bounds checks)

typedef __bf16 bf16_t;
typedef __bf16 bf16x8 __attribute__((ext_vector_type(8)));
typedef __bf16 bf16x4 __attribute__((ext_vector_type(4)));
typedef float  f32x4  __attribute__((ext_vector_type(4)));

static __device__ __forceinline__ bf16x8 ld_frag(const ushort* p) {
    return __builtin_bit_cast(bf16x8, *(const uint4*)p);
}

// global->LDS direct (async DMA), 16B per lane. LDS dest must be
// wave-uniform base + lane*16 — our staging layout is linear in tid so this holds.
typedef __attribute__((address_space(3))) ushort as3_ushort;
typedef __attribute__((address_space(1))) const ushort as1_ushort;
static __device__ __forceinline__ void gl_lds16(const ushort* g, ushort* l) {
    __builtin_amdgcn_global_load_lds((as1_ushort*)(uintptr_t)g,
                                     (as3_ushort*)(uintptr_t)l, 16, 0, 0);
}

// ---------------- cast / transpose ----------------

// x fp32 [NNODES,512] -> bf16 [MPAD,512], zero-filled pad rows.
__global__ void cast_x_kernel(const float* __restrict__ x, ushort* __restrict__ xb) {
    size_t t = (size_t)blockIdx.x * 256 + threadIdx.x;   // one thread = 4 elems
    size_t base = t * 4;
    int row = (int)(base >> 9);
    ushort4 pk;
    if (row < NNODES) {
        float4 v = *(const float4*)(x + base);
        pk.x = __builtin_bit_cast(ushort, (bf16_t)v.x);
        pk.y = __builtin_bit_cast(ushort, (bf16_t)v.y);
        pk.z = __builtin_bit_cast(ushort, (bf16_t)v.z);
        pk.w = __builtin_bit_cast(ushort, (bf16_t)v.w);
    } else {
        pk.x = pk.y = pk.z = pk.w = 0;
    }
    *(ushort4*)(xb + base) = pk;
}

// weight fp32 [K=512, N=512] -> wt bf16 [N, K] (transposed, row-major)
__global__ void cast_wt_kernel(const float* __restrict__ w, ushort* __restrict__ wt) {
    int t = blockIdx.x * 256 + threadIdx.x;   // 262144 threads
    int n = t >> 9, k = t & 511;
    wt[(size_t)n * 512 + k] = __builtin_bit_cast(ushort, (bf16_t)w[(size_t)k * 512 + n]);
}

// ---------------- GEMM: support = Xbf @ W  (bf16 in, bf16 out, fp32 acc) ----------------
// 128x128 tile / block of 256 threads; 4 waves each own a 64x64 quadrant (4x4 of 16x16).
// LDS layout [quad][row][8]: fragment = one aligned 16B ds_read; staging byte offset
// is tid*16 (linear), so global_load_lds width-16 applies directly (m97 pattern).
// Output written feature-split: sup[h][row][256], h = col>>8 (for spmm locality).
__global__ __launch_bounds__(256) void gemm_kernel(const ushort* __restrict__ xb,
                                                   const ushort* __restrict__ wt,
                                                   ushort* __restrict__ sup) {
    __shared__ ushort As[4 * 128 * 8];
    __shared__ ushort Bs[4 * 128 * 8];

    const int tid  = threadIdx.x;
    const int m0   = blockIdx.y * 128;
    const int n0   = blockIdx.x * 128;
    const int wave = tid >> 6, lane = tid & 63;
    const int quad = lane >> 4, r16 = lane & 15;
    const int wm = (wave >> 1) * 64, wn = (wave & 1) * 64;

    // staging: transfer L in [0,512): this thread does L=tid and L=tid+256
    const int qa = tid >> 7, ra = tid & 127;

    f32x4 acc[4][4];
#pragma unroll
    for (int i = 0; i < 4; ++i)
#pragma unroll
        for (int j = 0; j < 4; ++j) acc[i][j] = f32x4{0.f, 0.f, 0.f, 0.f};

    const size_t arow = (size_t)(m0 + ra) * 512;
    const size_t brow = (size_t)(n0 + ra) * 512;

    for (int kc = 0; kc < 16; ++kc) {
        const int k0 = kc * 32;
        __syncthreads();
        // As/Bs byte offset tid*16 and (tid+256)*16 == wave-uniform + lane*16
        gl_lds16(xb + arow + k0 + (qa    ) * 8, As + (size_t)tid * 8);
        gl_lds16(xb + arow + k0 + (qa + 2) * 8, As + (size_t)(tid + 256) * 8);
        gl_lds16(wt + brow + k0 + (qa    ) * 8, Bs + (size_t)tid * 8);
        gl_lds16(wt + brow + k0 + (qa + 2) * 8, Bs + (size_t)(tid + 256) * 8);
        __syncthreads();   // compiler drains vmcnt before s_barrier

        bf16x8 af[4], bfr[4];
#pragma unroll
        for (int i = 0; i < 4; ++i) af[i]  = ld_frag(As + (quad * 128 + wm + 16 * i + r16) * 8);
#pragma unroll
        for (int j = 0; j < 4; ++j) bfr[j] = ld_frag(Bs + (quad * 128 + wn + 16 * j + r16) * 8);

#pragma unroll
        for (int i = 0; i < 4; ++i)
#pragma unroll
            for (int j = 0; j < 4; ++j)
                acc[i][j] = __builtin_amdgcn_mfma_f32_16x16x32_bf16(af[i], bfr[j], acc[i][j], 0, 0, 0);
    }

    // epilogue: C/D layout col=lane&15, row=quad*4+reg; write to split layout
#pragma unroll
    for (int i = 0; i < 4; ++i) {
        const int rowb = m0 + wm + 16 * i + quad * 4;
#pragma unroll
        for (int j = 0; j < 4; ++j) {
            const int col = n0 + wn + 16 * j + r16;
            const size_t base = (size_t)(col >> 8) * MPAD * FHALF + (col & 255);
            f32x4 v = acc[i][j];
#pragma unroll
            for (int r = 0; r < 4; ++r)
                sup[base + (size_t)(rowb + r) * FHALF] = __builtin_bit_cast(ushort, (bf16_t)v[r]);
        }
    }
}

// ---------------- CSR build ----------------

__global__ void hist_kernel(const int* __restrict__ ei, int* __restrict__ cnt) {
    int e = blockIdx.x * 256 + threadIdx.x;
    if (e < NEDGES) atomicAdd(&cnt[ei[e]], 1);
}

// single-block exclusive scan over NNODES counts -> row_ptr.
// int4 vectorized: 25 16B loads per thread (was 98 scalar dependent loads).
__global__ __launch_bounds__(1024) void scan_kernel(const int* __restrict__ cnt, int* __restrict__ ptr) {
    __shared__ int sums[1024];
    const int t = threadIdx.x;
    const int CH = 100;                 // 1000 threads x 100 = 100000 exactly
    const int b = t * CH;
    int s = 0;
    if (t < 1000) {
        const int4* p = (const int4*)(cnt + b);
#pragma unroll
        for (int i = 0; i < 25; ++i) { int4 v = p[i]; s += v.x + v.y + v.z + v.w; }
    }
    sums[t] = s;
    __syncthreads();
    for (int off = 1; off < 1024; off <<= 1) {
        int v = (t >= off) ? sums[t - off] : 0;
        __syncthreads();
        sums[t] += v;
        __syncthreads();
    }
    if (t < 1000) {
        int run = sums[t] - s;          // exclusive prefix of this chunk
        const int4* p = (const int4*)(cnt + b);
        int4* q = (int4*)(ptr + b);
#pragma unroll
        for (int i = 0; i < 25; ++i) {
            int4 c = p[i];
            int4 r;
            r.x = run; r.y = run + c.x; r.z = r.y + c.y; r.w = r.z + c.z;
            q[i] = r;
            run = r.w + c.w;
        }
    }
    if (t == 0) ptr[NNODES] = NEDGES;
}

// packed edge records: one 8B store per edge (was two random 4B stores to
// separate arrays = two random cache lines; now one).
__global__ void scatter_kernel(const int* __restrict__ ei, const float* __restrict__ ew,
                               const int* __restrict__ ptr, int* __restrict__ fill,
                               uint2* __restrict__ epack) {
    int e = blockIdx.x * 256 + threadIdx.x;
    if (e < NEDGES) {
        int r = ei[e];
        int pos = ptr[r] + atomicAdd(&fill[r], 1);
        epack[pos] = make_uint2((unsigned)ei[NEDGES + e], __float_as_uint(ew[e]));
    }
}

// ---------------- SpMM: out[r] = sum_e w_e * sup[col_e] + bias ----------------
// sup is [2][MPAD][256] bf16 (feature-split). Launched 4x: 2 feature-halves x
// 2 row-halves (row split adds zero traffic; 4 dispatches lower the profiling
// visibility cutoff to ~110us). One wave per row; lane covers 4 features (8B
// gathers). Packed uint2 edge stream; out written nontemporal.
__global__ __launch_bounds__(256) void spmm_kernel(const ushort* __restrict__ sup,
                                                   const int* __restrict__ ptr,
                                                   const uint2* __restrict__ epack,
                                                   const float* __restrict__ bias,
                                                   float* __restrict__ out,
                                                   int half, int rbase) {
    const int row  = rbase + blockIdx.x * 4 + (threadIdx.x >> 6);
    const ushort* suph = sup + (size_t)half * MPAD * FHALF;
    const int lane = threadIdx.x & 63;
    const int fo   = lane * 4;               // feature offset within half
    const int start = ptr[row], end = ptr[row + 1];

    float acc[4];
#pragma unroll
    for (int j = 0; j < 4; ++j) acc[j] = 0.f;

    int i = start;
    for (; i + 4 <= end; i += 4) {
        const uint2 e0 = epack[i], e1 = epack[i + 1], e2 = epack[i + 2], e3 = epack[i + 3];
        const float w0 = __uint_as_float(e0.y), w1 = __uint_as_float(e1.y);
        const float w2 = __uint_as_float(e2.y), w3 = __uint_as_float(e3.y);
        const bf16x4 s0 = __builtin_bit_cast(bf16x4, *(const uint2*)(suph + (size_t)e0.x * FHALF + fo));
        const bf16x4 s1 = __builtin_bit_cast(bf16x4, *(const uint2*)(suph + (size_t)e1.x * FHALF + fo));
        const bf16x4 s2 = __builtin_bit_cast(bf16x4, *(const uint2*)(suph + (size_t)e2.x * FHALF + fo));
        const bf16x4 s3 = __builtin_bit_cast(bf16x4, *(const uint2*)(suph + (size_t)e3.x * FHALF + fo));
#pragma unroll
        for (int j = 0; j < 4; ++j) {
            acc[j] += w0 * (float)s0[j];
            acc[j] += w1 * (float)s1[j];
            acc[j] += w2 * (float)s2[j];
            acc[j] += w3 * (float)s3[j];
        }
    }
    for (; i < end; ++i) {
        const uint2 e = epack[i];
        const float w = __uint_as_float(e.y);
        const bf16x4 sv = __builtin_bit_cast(bf16x4, *(const uint2*)(suph + (size_t)e.x * FHALF + fo));
#pragma unroll
        for (int j = 0; j < 4; ++j) acc[j] += w * (float)sv[j];
    }

    const int fglob = half * FHALF + fo;
    const float4 b0 = *(const float4*)(bias + fglob);
    f32x4 o;
    o[0] = acc[0] + b0.x; o[1] = acc[1] + b0.y; o[2] = acc[2] + b0.z; o[3] = acc[3] + b0.w;
    __builtin_nontemporal_store(o, (f32x4*)(out + (size_t)row * 512 + fglob));
}

// ---------------- launch ----------------

extern "C" void kernel_launch(void* const* d_in, const int* in_sizes, int n_in,
                              void* d_out, int out_size, void* d_ws, size_t ws_size,
                              hipStream_t stream) {
    const float* x    = (const float*)d_in[0];
    const int*   ei   = (const int*)d_in[1];     // [2, E]
    const float* ew   = (const float*)d_in[2];
    const float* w    = (const float*)d_in[3];
    const float* bias = (const float*)d_in[4];
    float* out = (float*)d_out;

    char* ws = (char*)d_ws;
    size_t off = 0;
    auto take = [&](size_t bytes) { char* p = ws + off; off = (off + bytes + 255) & ~(size_t)255; return p; };

    ushort* xb   = (ushort*)take((size_t)MPAD * FDIM * 2);   // 102.5 MB
    ushort* sup  = (ushort*)take((size_t)MPAD * FDIM * 2);   // 102.5 MB (2 x [MPAD][256])
    ushort* wt   = (ushort*)take((size_t)FDIM * FDIM * 2);   // 0.5 MB
    int*   cnt   = (int*)take((size_t)NNODES * 4);           // cnt+fill adjacent -> one memset
    int*   fill  = (int*)take((size_t)NNODES * 4);
    int*   ptr   = (int*)take((size_t)(NNODES + 1) * 4);
    uint2* epack = (uint2*)take((size_t)NEDGES * 8);         // 25.6 MB packed (col,w)

    // zero cnt..fill in one memset (span includes the alignment pad between them)
    hipMemsetAsync(cnt, 0, (size_t)((char*)fill - (char*)cnt) + (size_t)NNODES * 4, stream);

    hipLaunchKernelGGL(cast_x_kernel, dim3((MPAD * FDIM / 4) / 256), dim3(256), 0, stream, x, xb);
    hipLaunchKernelGGL(cast_wt_kernel, dim3(1024), dim3(256), 0, stream, w, wt);
    hipLaunchKernelGGL(gemm_kernel, dim3(FDIM / 128, MPAD / 128), dim3(256), 0, stream, xb, wt, sup);
    hipLaunchKernelGGL(hist_kernel, dim3(NEDGES / 256), dim3(256), 0, stream, ei, cnt);
    hipLaunchKernelGGL(scan_kernel, dim3(1), dim3(1024), 0, stream, cnt, ptr);
    hipLaunchKernelGGL(scatter_kernel, dim3(NEDGES / 256), dim3(256), 0, stream, ei, ew, ptr, fill, epack);
    // 2 feature-halves x 2 row-halves
    hipLaunchKernelGGL(spmm_kernel, dim3(NNODES / 8), dim3(256), 0, stream, sup, ptr, epack, bias, out, 0, 0);
    hipLaunchKernelGGL(spmm_kernel, dim3(NNODES / 8), dim3(256), 0, stream, sup, ptr, epack, bias, out, 0, NNODES / 2);
    hipLaunchKernelGGL(spmm_kernel, dim3(NNODES / 8), dim3(256), 0, stream, sup, ptr, epack, bias, out, 1, 0);
    hipLaunchKernelGGL(spmm_kernel, dim3(NNODES / 8), dim3(256), 0, stream, sup, ptr, epack, bias, out, 1, NNODES / 2);
}